// Round 23
// baseline (820.257 us; speedup 1.0000x reference)
//
#include <hip/hip_runtime.h>
#include <hip/hip_fp16.h>
#include <stdint.h>

typedef __attribute__((ext_vector_type(8))) _Float16 half8;
typedef __attribute__((ext_vector_type(2))) _Float16 half2v;
typedef __attribute__((ext_vector_type(8))) short short8;
typedef __attribute__((ext_vector_type(4))) float floatx4;
typedef __attribute__((ext_vector_type(16))) float floatx16;
typedef __attribute__((ext_vector_type(2))) float float2v;

#define K_DIM 4096
#define N_DIM 11008
#define NQ_DIM 1376
#define NKT 64            // 64-k tiles (xb2 image granularity)
#define NS 128            // 32-k steps
#define MT2 32            // 256-row tiles
#define NTB 86            // 128-col tiles
// fallback geometry
#define BM 128
#define BN 128
#define NT_DIM 86
#define BK 32
#define NSTEPS 128

__device__ __forceinline__ uint32_t pkh(float a, float b) {
    half2v h; h[0] = (_Float16)a; h[1] = (_Float16)b;
    union { half2v h; uint32_t u; } c; c.h = h; return c.u;
}
__device__ __forceinline__ half2v u2h(uint32_t u) {
    union { uint32_t u; half2v h; } c; c.u = u; return c.h;
}
__device__ __forceinline__ uint32_t h2u(half2v h) {
    union { half2v h; uint32_t u; } c; c.h = h; return c.u;
}
#define GLDS(src, dst) __builtin_amdgcn_global_load_lds( \
    (const __attribute__((address_space(1))) void*)(src), \
    (__attribute__((address_space(3))) void*)(dst), 16, 0, 0)

// ---- pass 0a (fallback path only): x f32 -> f16 row-major ----
__global__ __launch_bounds__(256)
void cvt_x(const float* __restrict__ x, unsigned short* __restrict__ xb, int n8) {
    int i = blockIdx.x * 256 + threadIdx.x;
    const int stride = gridDim.x * 256;
    for (; i < n8; i += stride) {
        floatx4 a = *(const floatx4*)(x + (size_t)i * 8);
        floatx4 b = *(const floatx4*)(x + (size_t)i * 8 + 4);
        union { short8 v; uint32_t u[4]; } o;
        o.u[0] = pkh(a[0], a[1]);
        o.u[1] = pkh(a[2], a[3]);
        o.u[2] = pkh(b[0], b[1]);
        o.u[3] = pkh(b[2], b[3]);
        *(short8*)(xb + (size_t)i * 8) = o.v;
    }
}

// ---- pass 0a' (main path): x f32 -> TILED f16 image ----
// A(s) image (16KB, [kb4][row256][k8]) at halfs offset s*8192 within mt's region.
__global__ __launch_bounds__(512)
void cvt_x2(const float* __restrict__ x, unsigned short* __restrict__ xb2) {
    const int mt  = blockIdx.x;          // 0..31
    const int kt  = blockIdx.y;          // 0..63
    const int row = threadIdx.x & 255;
    const int kh  = threadIdx.x >> 8;    // 0/1
    const float* src = x + (size_t)(mt * 256 + row) * K_DIM + kt * 64 + kh * 32;
    unsigned short* dst = xb2 + (((size_t)(mt * 64 + kt)) * 2 + kh) * 8192 + row * 8;
#pragma unroll
    for (int kb = 0; kb < 4; ++kb) {
        floatx4 a = *(const floatx4*)(src + kb * 8);
        floatx4 b = *(const floatx4*)(src + kb * 8 + 4);
        union { half8 v; uint32_t u[4]; } o;
        o.u[0] = pkh(a[0], a[1]); o.u[1] = pkh(a[2], a[3]);
        o.u[2] = pkh(b[0], b[1]); o.u[3] = pkh(b[2], b[3]);
        *(half8*)(dst + kb * 2048) = o.v;
    }
}

// ---- pass 0b: dequantize W into per-(nt128, k32-step) 8KB images ----
__global__ __launch_bounds__(256)
void deq_w4(const int* __restrict__ qweight, const int* __restrict__ qzeros,
            const float* __restrict__ scales, unsigned short* __restrict__ wb) {
    const int nt = blockIdx.x;          // 0..85
    const int s  = blockIdx.y;          // 0..127
    const int c  = threadIdx.x & 127;   // local col
    const int kh = threadIdx.x >> 7;    // 0/1 -> kb pair
    const int g  = s >> 2;
    const int col  = nt * 128 + c;
    const int sh   = ((c & 1) ? 16 : 0) + ((c & 7) >> 1) * 4;   // AWQ inverse order
    const int word = nt * 16 + (c >> 3);

    const uint32_t zw = (uint32_t)qzeros[(size_t)g * NQ_DIM + word];
    const uint32_t zn = ((zw >> sh) & 0xFu) | 0x6400u;          // 1024 + z
    const half2v zt = u2h(zn | (zn << 16));
    const float sc = scales[(size_t)g * N_DIM + col];
    half2v st; st[0] = (_Float16)sc; st[1] = (_Float16)sc;

    const int* qp = qweight + (size_t)(s * 32 + kh * 16) * NQ_DIM + word;
    unsigned short* wt = wb + ((size_t)nt * NS + s) * 4096;

#pragma unroll
    for (int h = 0; h < 2; ++h) {                               // kb = kh*2 + h
        union { half8 v; uint32_t u[4]; } o;
#pragma unroll
        for (int p = 0; p < 4; ++p) {
            const uint32_t qa = (uint32_t)qp[(size_t)(h * 8 + 2 * p)     * NQ_DIM];
            const uint32_t qb = (uint32_t)qp[(size_t)(h * 8 + 2 * p + 1) * NQ_DIM];
            uint32_t u = ((qa >> sh) & 0xFu) | (((qb >> sh) & 0xFu) << 16) | 0x64006400u;
            o.u[p] = h2u((u2h(u) - zt) * st);                   // exact int sub, fp16 mul
        }
        *(half8*)(wt + (size_t)((kh * 2 + h) * 1024 + c * 8)) = o.v;
    }
}

// ---- main GEMM: 256x128 tile, k-step 32, 512 thr (8 waves 4Mx2N, 64x64/wave) ----
// R22 = R21 structure with 32x32x16 MFMA: 8 MFMA/step (vs 16), same 8 ds_reads.
// A ring-3 (48KB) + B ring-3 (24KB) = 72KB -> 2 blocks/CU (4 waves/SIMD, 2 blocks).
// Step: {8 ds_read; 3 GLDS stage; barrier; 8 MFMA; vmcnt(3); barrier}.
__global__ __launch_bounds__(512, 4)
void awq_gemm16(const unsigned short* __restrict__ xb2,
                const unsigned short* __restrict__ wb,
                const float* __restrict__ bias,
                float* __restrict__ out)
{
    __shared__ char lds[73728] __attribute__((aligned(128)));
    // A region r at r*16384 (r=0..2); B region r at 49152 + r*8192.

    const int tid  = threadIdx.x;
    const int lane = tid & 63;
    const int wid  = tid >> 6;          // 0..7
    const int wr   = wid >> 1;          // M quarter (0..3): 64 rows
    const int wc   = wid & 1;           // N half (0..1): 64 cols

    // 2-D window swizzle: groups of 16nt x 32mt (512 ids)
    const int flat = blockIdx.y * NTB + blockIdx.x;   // 0..2751
    int nt, mt;
    if (flat < 2560) {
        const int g = flat >> 9;
        const int r = flat & 511;
        nt = g * 16 + (r & 15);
        mt = r >> 4;
    } else {
        const int r = flat - 2560;       // 0..191
        mt = r / 6;
        nt = 80 + (r - mt * 6);
    }
    const int n0 = nt * 128;
    const int m0 = mt * 256;

    // stage source pointers (advance by constant stride; stage source = step s+2)
    const unsigned short* asrc = xb2 + (size_t)mt * NKT * 2 * 8192 + wid * 512 + lane * 8;
    const unsigned short* bsrc = wb  + (size_t)nt * NS * 4096      + wid * 512 + lane * 8;

    // 32x32 fragment read offsets: lane l holds row/col (l&31), kb = 2t + (l>>5).
    const int l31 = lane & 31;
    const int lhi = lane >> 5;
    const int aoff = lhi * 4096 + (wr * 64 + l31) * 16;   // + t*8192 + m*512
    const int boff = lhi * 2048 + (wc * 64 + l31) * 16;   // + t*4096 + n*512
    const int sA = wid * 1024;
    const int sB = wid * 1024;

    floatx16 acc[2][2];
#pragma unroll
    for (int i = 0; i < 2; ++i)
#pragma unroll
        for (int j = 0; j < 2; ++j)
            acc[i][j] = (floatx16)(0.f);

    auto stage = [&](int RS, bool advance) {
        char* ab = &lds[RS * 16384 + sA];
        GLDS(asrc, ab);
        GLDS(asrc + 4096, ab + 8192);
        char* bb = &lds[49152 + RS * 8192 + sB];
        GLDS(bsrc, bb);
        if (advance) { asrc += 8192; bsrc += 4096; }
    };
    auto step = [&](int R, int RS, bool advance) {
        const char* abase = &lds[R * 16384];
        const char* bbase = &lds[49152 + R * 8192];
        half8 af[2][2], bf[2][2];
#pragma unroll
        for (int t = 0; t < 2; ++t) {
#pragma unroll
            for (int n = 0; n < 2; ++n)
                bf[t][n] = *(const half8*)(bbase + boff + t * 4096 + n * 512);
#pragma unroll
            for (int m = 0; m < 2; ++m)
                af[t][m] = *(const half8*)(abase + aoff + t * 8192 + m * 512);
        }

        stage(RS, advance);

        __builtin_amdgcn_s_barrier();
        __builtin_amdgcn_s_setprio(1);
#pragma unroll
        for (int t = 0; t < 2; ++t)
#pragma unroll
            for (int m = 0; m < 2; ++m)
#pragma unroll
                for (int n = 0; n < 2; ++n)
                    acc[m][n] = __builtin_amdgcn_mfma_f32_32x32x16_f16(af[t][m], bf[t][n], acc[m][n], 0, 0, 0);
        __builtin_amdgcn_s_setprio(0);
        asm volatile("s_waitcnt vmcnt(3)" ::: "memory");   // s+1's 3 loads landed; s+2 flies
        __builtin_amdgcn_s_barrier();
    };

    // ---- prologue: stage s=0 -> r0, s=1 -> r1 (asrc/bsrc end at s=2) ----
    stage(0, true);
    stage(1, true);
    asm volatile("s_waitcnt vmcnt(3)" ::: "memory");       // s=0 landed; s=1 in flight
    __builtin_amdgcn_s_barrier();

    // main: s = 0..122 (41 x 3), all advance
    for (int tt = 0; tt < 41; ++tt) {
        step(0, 2, true);
        step(1, 0, true);
        step(2, 1, true);
    }
    // tail: s=123..127 (dummy re-stages target dead regions)
    step(0, 2, true);    // s=123
    step(1, 0, true);    // s=124
    step(2, 1, false);   // s=125
    step(0, 2, false);   // s=126
    step(1, 0, false);   // s=127

    // epilogue: 32x32 C/D -> col = n0+wc*64+n*32+(lane&31),
    // row = m0+wr*64+m*32+4*(lane>>5)+8*(reg>>2)+(reg&3)  [m74/m101, R19-verified]
    const int colb = n0 + wc * 64 + l31;
    const int rowb = m0 + wr * 64 + 4 * lhi;
#pragma unroll
    for (int n = 0; n < 2; ++n) {
        const int col = colb + n * 32;
        const float bias_f = bias[col];
#pragma unroll
        for (int m = 0; m < 2; ++m) {
            const int rowm = rowb + m * 32;
#pragma unroll
            for (int reg = 0; reg < 16; ++reg) {
                const int row = rowm + (reg & 3) + 8 * (reg >> 2);
                __builtin_nontemporal_store(acc[m][n][reg] + bias_f,
                                            &out[(size_t)row * N_DIM + col]);
            }
        }
    }
    asm volatile("s_waitcnt vmcnt(0) lgkmcnt(0)" ::: "memory");
}

// ================= fused fallback (ws too small) =================
template <bool PRECVT>
__global__ __launch_bounds__(256, 3)
void awq_gemm5(const float* __restrict__ xf,
               const unsigned short* __restrict__ xb,
               const int* __restrict__ qweight,
               const int* __restrict__ qzeros,
               const float* __restrict__ scales,
               const float* __restrict__ bias,
               float* __restrict__ out)
{
    __shared__ char lds[32768] __attribute__((aligned(128)));
    const int tid  = threadIdx.x;
    const int lane = tid & 63;
    const int wid  = tid >> 6;
    const int n0 = blockIdx.x * BN;
    const int m0 = blockIdx.y * BM;

    const unsigned short* agl0 = xb + (size_t)(m0 + lane) * K_DIM + wid * 8;
    const unsigned short* agl1 = xb + (size_t)(m0 + 64 + lane) * K_DIM + wid * 8;
    const float* aptr = xf + (size_t)(m0 + (tid >> 1)) * K_DIM + (tid & 1) * 16;
    const int awr = ((tid & 1) * 2) * 2048 + (tid >> 1) * 16;

    const int nq      = tid & 15;
    const int k_local = (tid >> 4) * 2;
    const int kb_w    = k_local >> 3;
    const int k8      = k_local & 7;
    const int nq7     = nq & 7;
    const int* qp0 = qweight + blockIdx.x * 16 + nq + (size_t)k_local * NQ_DIM;
    const int* qp1 = qp0 + NQ_DIM;
    const int* zp  = qzeros + blockIdx.x * 16 + nq;
    const float* sp = scales + n0 + nq * 8;
    int baddr[8];
#pragma unroll
    for (int j = 0; j < 8; ++j)
        baddr[j] = 16384 + (kb_w * 128 + nq * 8 + (j ^ nq7)) * 16 + k8 * 2;

    const int wm = (wid >> 1) * 64;
    const int wn = (wid & 1) * 64;
    const int lm = lane & 15;
    const int kb_l = lane >> 4;
    const int aoff = kb_l * 2048 + (wm + lm) * 16;
    int boff[4];
#pragma unroll
    for (int j = 0; j < 4; ++j) {
        int blk = kb_l * 128 + wn + j * 16 + lm;
        blk ^= (blk >> 3) & 7;
        boff[j] = 16384 + blk * 16;
    }

    floatx4 acc[4][4];
#pragma unroll
    for (int i = 0; i < 4; ++i)
#pragma unroll
        for (int j = 0; j < 4; ++j)
            acc[i][j] = (floatx4){0.f, 0.f, 0.f, 0.f};

    half2v zt[4], st[4];
    uint32_t q0, q1;

    auto stage_a = [&](int abase) {
        if constexpr (PRECVT) {
            GLDS(agl0, &lds[abase + wid * 2048]);
            GLDS(agl1, &lds[abase + wid * 2048 + 1024]);
            agl0 += BK; agl1 += BK;
        } else {
            floatx4 a0 = *(const floatx4*)(aptr + 0);
            floatx4 a1 = *(const floatx4*)(aptr + 4);
            floatx4 a2 = *(const floatx4*)(aptr + 8);
            floatx4 a3 = *(const floatx4*)(aptr + 12);
            aptr += BK;
            union { short8 v; uint32_t u[4]; } o0, o1;
            o0.u[0] = pkh(a0[0], a0[1]); o0.u[1] = pkh(a0[2], a0[3]);
            o0.u[2] = pkh(a1[0], a1[1]); o0.u[3] = pkh(a1[2], a1[3]);
            o1.u[0] = pkh(a2[0], a2[1]); o1.u[1] = pkh(a2[2], a2[3]);
            o1.u[2] = pkh(a3[0], a3[1]); o1.u[3] = pkh(a3[2], a3[3]);
            *(short8*)&lds[abase + awr]        = o0.v;
            *(short8*)&lds[abase + awr + 2048] = o1.v;
        }
    };
    auto load_q = [&]() {
        q0 = (uint32_t)*qp0; q1 = (uint32_t)*qp1;
        qp0 += (size_t)BK * NQ_DIM; qp1 += (size_t)BK * NQ_DIM;
    };
    auto refresh = [&]() {
        const uint32_t zw = (uint32_t)*zp;
        zp += NQ_DIM;
#pragma unroll
        for (int l = 0; l < 4; ++l) {
            zt[l] = u2h(((zw >> (4 * l)) & 0x000F000Fu) | 0x64006400u);
            float2v s2 = *(const float2v*)(sp + 2 * l);
            half2v sh2; sh2[0] = (_Float16)s2[0]; sh2[1] = (_Float16)s2[1];
            st[l] = sh2;
        }
        sp += N_DIM;
    };
    auto deq_store = [&](int off) {
#pragma unroll
        for (int l = 0; l < 4; ++l) {
            uint32_t t0 = ((q0 >> (4 * l)) & 0x000F000Fu) | 0x64006400u;
            uint32_t t1 = ((q1 >> (4 * l)) & 0x000F000Fu) | 0x64006400u;
            half2v w0 = (u2h(t0) - zt[l]) * st[l];
            half2v w1 = (u2h(t1) - zt[l]) * st[l];
            uint32_t p0 = h2u(w0), p1 = h2u(w1);
            uint32_t de = (p0 & 0xFFFFu) | (p1 << 16);
            uint32_t dd = (p0 >> 16) | (p1 & 0xFFFF0000u);
            *(uint32_t*)&lds[baddr[2 * l]     + off] = de;
            *(uint32_t*)&lds[baddr[2 * l + 1] + off] = dd;
        }
    };
    auto compute = [&](int ab, int bb) {
        half8 af[4], bfr[4];
#pragma unroll
        for (int i = 0; i < 4; ++i) af[i] = *(const half8*)&lds[ab + aoff + i * 256];
#pragma unroll
        for (int j = 0; j < 4; ++j) bfr[j] = *(const half8*)&lds[bb + boff[j] - 16384];
#pragma unroll
        for (int i = 0; i < 4; ++i)
#pragma unroll
            for (int j = 0; j < 4; ++j)
                acc[i][j] = __builtin_amdgcn_mfma_f32_16x16x32_f16(af[i], bfr[j], acc[i][j], 0, 0, 0);
    };

    stage_a(0); load_q(); refresh(); deq_store(0); load_q();
    __syncthreads();

    for (int t = 0; t < NSTEPS; t += 2) {
        stage_a(8192);
        deq_store(8192);
        if (t + 2 < NSTEPS) load_q();
        compute(0, 16384);
        __syncthreads();
        if (t + 2 < NSTEPS) {
            stage_a(0);
            if (((t + 2) & 3) == 0) refresh();
            deq_store(0);
            if (t + 3 < NSTEPS) load_q();
        }
        compute(8192, 24576);
        __syncthreads();
    }

    const int colb = n0 + wn + lm;
    const int rowb = m0 + wm + (kb_l << 2);
#pragma unroll
    for (int j = 0; j < 4; ++j) {
        const int col = colb + j * 16;
        const float bias_f = bias[col];
#pragma unroll
        for (int i = 0; i < 4; ++i) {
            const int row = rowb + i * 16;
#pragma unroll
            for (int r4 = 0; r4 < 4; ++r4) {
                out[(size_t)(row + r4) * N_DIM + col] = acc[i][j][r4] + bias_f;
            }
        }
    }
}

extern "C" void kernel_launch(void* const* d_in, const int* in_sizes, int n_in,
                              void* d_out, int out_size, void* d_ws, size_t ws_size,
                              hipStream_t stream) {
    const float* x    = (const float*)d_in[0];
    const int* qw     = (const int*)d_in[1];
    const int* qz     = (const int*)d_in[2];
    const float* sc   = (const float*)d_in[3];
    const float* bi   = (const float*)d_in[4];
    float* out        = (float*)d_out;

    const int M = in_sizes[0] / K_DIM;                       // 8192
    const size_t xb_bytes = (size_t)M * K_DIM * 2;           // 64 MiB
    const size_t wb_bytes = (size_t)K_DIM * N_DIM * 2;       // 86 MiB

    if (ws_size >= xb_bytes + wb_bytes) {
        unsigned short* xb2 = (unsigned short*)d_ws;
        unsigned short* wb  = (unsigned short*)((char*)d_ws + xb_bytes);
        cvt_x2<<<dim3(MT2, NKT), 512, 0, stream>>>(x, xb2);
        deq_w4<<<dim3(NTB, NS), 256, 0, stream>>>(qw, qz, sc, wb);
        awq_gemm16<<<dim3(NTB, MT2), 512, 0, stream>>>(xb2, wb, bi, out);
    } else if (ws_size >= xb_bytes) {
        unsigned short* xb = (unsigned short*)d_ws;
        const int n8 = (int)((size_t)M * K_DIM / 8);
        cvt_x<<<2048, 256, 0, stream>>>(x, xb, n8);
        awq_gemm5<true><<<dim3(NT_DIM, M / BM), 256, 0, stream>>>(x, xb, qw, qz, sc, bi, out);
    } else {
        awq_gemm5<false><<<dim3(NT_DIM, M / BM), 256, 0, stream>>>(x, nullptr, qw, qz, sc, bi, out);
    }
}

// Round 24
// 720.714 us; speedup vs baseline: 1.1381x; 1.1381x over previous
//
#include <hip/hip_runtime.h>
#include <hip/hip_fp16.h>
#include <stdint.h>

typedef __attribute__((ext_vector_type(8))) _Float16 half8;
typedef __attribute__((ext_vector_type(2))) _Float16 half2v;
typedef __attribute__((ext_vector_type(8))) short short8;
typedef __attribute__((ext_vector_type(4))) float floatx4;
typedef __attribute__((ext_vector_type(2))) float float2v;

#define K_DIM 4096
#define N_DIM 11008
#define NQ_DIM 1376
#define NKT 64            // 64-k tiles (xb2 image granularity)
#define NS 128            // 32-k steps
#define MT2 32            // 256-row tiles
#define NTB 86            // 128-col tiles
// fallback geometry
#define BM 128
#define BN 128
#define NT_DIM 86
#define BK 32
#define NSTEPS 128

__device__ __forceinline__ uint32_t pkh(float a, float b) {
    half2v h; h[0] = (_Float16)a; h[1] = (_Float16)b;
    union { half2v h; uint32_t u; } c; c.h = h; return c.u;
}
__device__ __forceinline__ half2v u2h(uint32_t u) {
    union { uint32_t u; half2v h; } c; c.u = u; return c.h;
}
__device__ __forceinline__ uint32_t h2u(half2v h) {
    union { half2v h; uint32_t u; } c; c.h = h; return c.u;
}
#define GLDS(src, dst) __builtin_amdgcn_global_load_lds( \
    (const __attribute__((address_space(1))) void*)(src), \
    (__attribute__((address_space(3))) void*)(dst), 16, 0, 0)

// ---- pass 0a (fallback path only): x f32 -> f16 row-major ----
__global__ __launch_bounds__(256)
void cvt_x(const float* __restrict__ x, unsigned short* __restrict__ xb, int n8) {
    int i = blockIdx.x * 256 + threadIdx.x;
    const int stride = gridDim.x * 256;
    for (; i < n8; i += stride) {
        floatx4 a = *(const floatx4*)(x + (size_t)i * 8);
        floatx4 b = *(const floatx4*)(x + (size_t)i * 8 + 4);
        union { short8 v; uint32_t u[4]; } o;
        o.u[0] = pkh(a[0], a[1]);
        o.u[1] = pkh(a[2], a[3]);
        o.u[2] = pkh(b[0], b[1]);
        o.u[3] = pkh(b[2], b[3]);
        *(short8*)(xb + (size_t)i * 8) = o.v;
    }
}

// ---- pass 0a' (main path): x f32 -> TILED f16 image ----
// A(s) image (16KB, [kb4][row256][k8]) at halfs offset s*8192 within mt's region.
__global__ __launch_bounds__(512)
void cvt_x2(const float* __restrict__ x, unsigned short* __restrict__ xb2) {
    const int mt  = blockIdx.x;          // 0..31
    const int kt  = blockIdx.y;          // 0..63
    const int row = threadIdx.x & 255;
    const int kh  = threadIdx.x >> 8;    // 0/1
    const float* src = x + (size_t)(mt * 256 + row) * K_DIM + kt * 64 + kh * 32;
    unsigned short* dst = xb2 + (((size_t)(mt * 64 + kt)) * 2 + kh) * 8192 + row * 8;
#pragma unroll
    for (int kb = 0; kb < 4; ++kb) {
        floatx4 a = *(const floatx4*)(src + kb * 8);
        floatx4 b = *(const floatx4*)(src + kb * 8 + 4);
        union { half8 v; uint32_t u[4]; } o;
        o.u[0] = pkh(a[0], a[1]); o.u[1] = pkh(a[2], a[3]);
        o.u[2] = pkh(b[0], b[1]); o.u[3] = pkh(b[2], b[3]);
        *(half8*)(dst + kb * 2048) = o.v;
    }
}

// ---- pass 0b: dequantize W into per-(nt128, k32-step) 8KB images ----
__global__ __launch_bounds__(256)
void deq_w4(const int* __restrict__ qweight, const int* __restrict__ qzeros,
            const float* __restrict__ scales, unsigned short* __restrict__ wb) {
    const int nt = blockIdx.x;          // 0..85
    const int s  = blockIdx.y;          // 0..127
    const int c  = threadIdx.x & 127;   // local col
    const int kh = threadIdx.x >> 7;    // 0/1 -> kb pair
    const int g  = s >> 2;
    const int col  = nt * 128 + c;
    const int sh   = ((c & 1) ? 16 : 0) + ((c & 7) >> 1) * 4;   // AWQ inverse order
    const int word = nt * 16 + (c >> 3);

    const uint32_t zw = (uint32_t)qzeros[(size_t)g * NQ_DIM + word];
    const uint32_t zn = ((zw >> sh) & 0xFu) | 0x6400u;          // 1024 + z
    const half2v zt = u2h(zn | (zn << 16));
    const float sc = scales[(size_t)g * N_DIM + col];
    half2v st; st[0] = (_Float16)sc; st[1] = (_Float16)sc;

    const int* qp = qweight + (size_t)(s * 32 + kh * 16) * NQ_DIM + word;
    unsigned short* wt = wb + ((size_t)nt * NS + s) * 4096;

#pragma unroll
    for (int h = 0; h < 2; ++h) {                               // kb = kh*2 + h
        union { half8 v; uint32_t u[4]; } o;
#pragma unroll
        for (int p = 0; p < 4; ++p) {
            const uint32_t qa = (uint32_t)qp[(size_t)(h * 8 + 2 * p)     * NQ_DIM];
            const uint32_t qb = (uint32_t)qp[(size_t)(h * 8 + 2 * p + 1) * NQ_DIM];
            uint32_t u = ((qa >> sh) & 0xFu) | (((qb >> sh) & 0xFu) << 16) | 0x64006400u;
            o.u[p] = h2u((u2h(u) - zt) * st);                   // exact int sub, fp16 mul
        }
        *(half8*)(wt + (size_t)((kh * 2 + h) * 1024 + c * 8)) = o.v;
    }
}

// ---- main GEMM: 256x128 tile, k-step 32, 512 thr (8 waves 4Mx2N, 64x64/wave) ----
// R24 = R21 (16x16x32, ring-3 A+B, merged phase) minus the redundant pre-MFMA
// barrier: ONE barrier per step. Correctness: reads(s) target region s%3;
// stages(s) target (s-1)%3 (disjoint); region (s-1)%3's reads completed before
// step s-1's MFMAs, hence before its closing barrier, hence before stage(s);
// reads(s) validated by vmcnt(3)+barrier at end of step s-1.
__global__ __launch_bounds__(512, 4)
void awq_gemm17(const unsigned short* __restrict__ xb2,
                const unsigned short* __restrict__ wb,
                const float* __restrict__ bias,
                float* __restrict__ out)
{
    __shared__ char lds[73728] __attribute__((aligned(128)));
    // A region r at r*16384 (r=0..2); B region r at 49152 + r*8192.

    const int tid  = threadIdx.x;
    const int lane = tid & 63;
    const int wid  = tid >> 6;          // 0..7
    const int wr   = wid >> 1;          // M quarter (0..3): 64 rows
    const int wc   = wid & 1;           // N half (0..1): 64 cols

    // 2-D window swizzle: groups of 16nt x 32mt (512 ids)
    const int flat = blockIdx.y * NTB + blockIdx.x;   // 0..2751
    int nt, mt;
    if (flat < 2560) {
        const int g = flat >> 9;
        const int r = flat & 511;
        nt = g * 16 + (r & 15);
        mt = r >> 4;
    } else {
        const int r = flat - 2560;       // 0..191
        mt = r / 6;
        nt = 80 + (r - mt * 6);
    }
    const int n0 = nt * 128;
    const int m0 = mt * 256;

    // stage source pointers (advance by constant stride; stage source = step s+2)
    const unsigned short* asrc = xb2 + (size_t)mt * NKT * 2 * 8192 + wid * 512 + lane * 8;
    const unsigned short* bsrc = wb  + (size_t)nt * NS * 4096      + wid * 512 + lane * 8;

    // fragment read offsets (within-region)
    const int lm = lane & 15;
    const int kb_l = lane >> 4;
    const int aoff = kb_l * 4096 + (wr * 64 + lm) * 16;    // + m*256
    const int boff = kb_l * 2048 + (wc * 64 + lm) * 16;    // + n*256
    const int sA = wid * 1024;                             // stage LDS offset (A region)
    const int sB = wid * 1024;                             // stage LDS offset (B region)

    floatx4 acc[4][4];
#pragma unroll
    for (int i = 0; i < 4; ++i)
#pragma unroll
        for (int j = 0; j < 4; ++j)
            acc[i][j] = (floatx4){0.f, 0.f, 0.f, 0.f};

    auto stage = [&](int RS, bool advance) {
        char* ab = &lds[RS * 16384 + sA];
        GLDS(asrc, ab);
        GLDS(asrc + 4096, ab + 8192);
        char* bb = &lds[49152 + RS * 8192 + sB];
        GLDS(bsrc, bb);
        if (advance) { asrc += 8192; bsrc += 4096; }
    };
    auto step = [&](int R, int RS, bool advance) {
        const char* abase = &lds[R * 16384];
        const char* bbase = &lds[49152 + R * 8192];
        half8 af[4], bf[4];
#pragma unroll
        for (int n = 0; n < 4; ++n)
            bf[n] = *(const half8*)(bbase + boff + n * 256);
#pragma unroll
        for (int m = 0; m < 4; ++m)
            af[m] = *(const half8*)(abase + aoff + m * 256);

        stage(RS, advance);

        __builtin_amdgcn_s_setprio(1);
#pragma unroll
        for (int m = 0; m < 4; ++m)
#pragma unroll
            for (int n = 0; n < 4; ++n)
                acc[m][n] = __builtin_amdgcn_mfma_f32_16x16x32_f16(af[m], bf[n], acc[m][n], 0, 0, 0);
        __builtin_amdgcn_s_setprio(0);
        asm volatile("s_waitcnt vmcnt(3)" ::: "memory");   // s+1's 3 loads landed; s+2 flies
        __builtin_amdgcn_s_barrier();
    };

    // ---- prologue: stage s=0 -> r0, s=1 -> r1 (asrc/bsrc end at s=2) ----
    stage(0, true);
    stage(1, true);
    asm volatile("s_waitcnt vmcnt(3)" ::: "memory");       // s=0 landed; s=1 in flight
    __builtin_amdgcn_s_barrier();

    // main: s = 0..122 (41 x 3), all advance
    for (int tt = 0; tt < 41; ++tt) {
        step(0, 2, true);
        step(1, 0, true);
        step(2, 1, true);
    }
    // tail: s=123..127 (dummy re-stages target dead regions)
    step(0, 2, true);    // s=123
    step(1, 0, true);    // s=124
    step(2, 1, false);   // s=125
    step(0, 2, false);   // s=126
    step(1, 0, false);   // s=127

    // epilogue: C/D col = lane&15, row = (lane>>4)*4 + r4 ; non-temporal stores
    const int colb = n0 + wc * 64 + lm;
    const int rowb = m0 + wr * 64 + (kb_l << 2);
#pragma unroll
    for (int n = 0; n < 4; ++n) {
        const int col = colb + n * 16;
        const float bias_f = bias[col];
#pragma unroll
        for (int m = 0; m < 4; ++m) {
            const int row = rowb + m * 16;
#pragma unroll
            for (int r4 = 0; r4 < 4; ++r4) {
                __builtin_nontemporal_store(acc[m][n][r4] + bias_f,
                                            &out[(size_t)(row + r4) * N_DIM + col]);
            }
        }
    }
    asm volatile("s_waitcnt vmcnt(0) lgkmcnt(0)" ::: "memory");
}

// ================= fused fallback (ws too small) =================
template <bool PRECVT>
__global__ __launch_bounds__(256, 3)
void awq_gemm5(const float* __restrict__ xf,
               const unsigned short* __restrict__ xb,
               const int* __restrict__ qweight,
               const int* __restrict__ qzeros,
               const float* __restrict__ scales,
               const float* __restrict__ bias,
               float* __restrict__ out)
{
    __shared__ char lds[32768] __attribute__((aligned(128)));
    const int tid  = threadIdx.x;
    const int lane = tid & 63;
    const int wid  = tid >> 6;
    const int n0 = blockIdx.x * BN;
    const int m0 = blockIdx.y * BM;

    const unsigned short* agl0 = xb + (size_t)(m0 + lane) * K_DIM + wid * 8;
    const unsigned short* agl1 = xb + (size_t)(m0 + 64 + lane) * K_DIM + wid * 8;
    const float* aptr = xf + (size_t)(m0 + (tid >> 1)) * K_DIM + (tid & 1) * 16;
    const int awr = ((tid & 1) * 2) * 2048 + (tid >> 1) * 16;

    const int nq      = tid & 15;
    const int k_local = (tid >> 4) * 2;
    const int kb_w    = k_local >> 3;
    const int k8      = k_local & 7;
    const int nq7     = nq & 7;
    const int* qp0 = qweight + blockIdx.x * 16 + nq + (size_t)k_local * NQ_DIM;
    const int* qp1 = qp0 + NQ_DIM;
    const int* zp  = qzeros + blockIdx.x * 16 + nq;
    const float* sp = scales + n0 + nq * 8;
    int baddr[8];
#pragma unroll
    for (int j = 0; j < 8; ++j)
        baddr[j] = 16384 + (kb_w * 128 + nq * 8 + (j ^ nq7)) * 16 + k8 * 2;

    const int wm = (wid >> 1) * 64;
    const int wn = (wid & 1) * 64;
    const int lm = lane & 15;
    const int kb_l = lane >> 4;
    const int aoff = kb_l * 2048 + (wm + lm) * 16;
    int boff[4];
#pragma unroll
    for (int j = 0; j < 4; ++j) {
        int blk = kb_l * 128 + wn + j * 16 + lm;
        blk ^= (blk >> 3) & 7;
        boff[j] = 16384 + blk * 16;
    }

    floatx4 acc[4][4];
#pragma unroll
    for (int i = 0; i < 4; ++i)
#pragma unroll
        for (int j = 0; j < 4; ++j)
            acc[i][j] = (floatx4){0.f, 0.f, 0.f, 0.f};

    half2v zt[4], st[4];
    uint32_t q0, q1;

    auto stage_a = [&](int abase) {
        if constexpr (PRECVT) {
            GLDS(agl0, &lds[abase + wid * 2048]);
            GLDS(agl1, &lds[abase + wid * 2048 + 1024]);
            agl0 += BK; agl1 += BK;
        } else {
            floatx4 a0 = *(const floatx4*)(aptr + 0);
            floatx4 a1 = *(const floatx4*)(aptr + 4);
            floatx4 a2 = *(const floatx4*)(aptr + 8);
            floatx4 a3 = *(const floatx4*)(aptr + 12);
            aptr += BK;
            union { short8 v; uint32_t u[4]; } o0, o1;
            o0.u[0] = pkh(a0[0], a0[1]); o0.u[1] = pkh(a0[2], a0[3]);
            o0.u[2] = pkh(a1[0], a1[1]); o0.u[3] = pkh(a1[2], a1[3]);
            o1.u[0] = pkh(a2[0], a2[1]); o1.u[1] = pkh(a2[2], a2[3]);
            o1.u[2] = pkh(a3[0], a3[1]); o1.u[3] = pkh(a3[2], a3[3]);
            *(short8*)&lds[abase + awr]        = o0.v;
            *(short8*)&lds[abase + awr + 2048] = o1.v;
        }
    };
    auto load_q = [&]() {
        q0 = (uint32_t)*qp0; q1 = (uint32_t)*qp1;
        qp0 += (size_t)BK * NQ_DIM; qp1 += (size_t)BK * NQ_DIM;
    };
    auto refresh = [&]() {
        const uint32_t zw = (uint32_t)*zp;
        zp += NQ_DIM;
#pragma unroll
        for (int l = 0; l < 4; ++l) {
            zt[l] = u2h(((zw >> (4 * l)) & 0x000F000Fu) | 0x64006400u);
            float2v s2 = *(const float2v*)(sp + 2 * l);
            half2v sh2; sh2[0] = (_Float16)s2[0]; sh2[1] = (_Float16)s2[1];
            st[l] = sh2;
        }
        sp += N_DIM;
    };
    auto deq_store = [&](int off) {
#pragma unroll
        for (int l = 0; l < 4; ++l) {
            uint32_t t0 = ((q0 >> (4 * l)) & 0x000F000Fu) | 0x64006400u;
            uint32_t t1 = ((q1 >> (4 * l)) & 0x000F000Fu) | 0x64006400u;
            half2v w0 = (u2h(t0) - zt[l]) * st[l];
            half2v w1 = (u2h(t1) - zt[l]) * st[l];
            uint32_t p0 = h2u(w0), p1 = h2u(w1);
            uint32_t de = (p0 & 0xFFFFu) | (p1 << 16);
            uint32_t dd = (p0 >> 16) | (p1 & 0xFFFF0000u);
            *(uint32_t*)&lds[baddr[2 * l]     + off] = de;
            *(uint32_t*)&lds[baddr[2 * l + 1] + off] = dd;
        }
    };
    auto compute = [&](int ab, int bb) {
        half8 af[4], bfr[4];
#pragma unroll
        for (int i = 0; i < 4; ++i) af[i] = *(const half8*)&lds[ab + aoff + i * 256];
#pragma unroll
        for (int j = 0; j < 4; ++j) bfr[j] = *(const half8*)&lds[bb + boff[j] - 16384];
#pragma unroll
        for (int i = 0; i < 4; ++i)
#pragma unroll
            for (int j = 0; j < 4; ++j)
                acc[i][j] = __builtin_amdgcn_mfma_f32_16x16x32_f16(af[i], bfr[j], acc[i][j], 0, 0, 0);
    };

    stage_a(0); load_q(); refresh(); deq_store(0); load_q();
    __syncthreads();

    for (int t = 0; t < NSTEPS; t += 2) {
        stage_a(8192);
        deq_store(8192);
        if (t + 2 < NSTEPS) load_q();
        compute(0, 16384);
        __syncthreads();
        if (t + 2 < NSTEPS) {
            stage_a(0);
            if (((t + 2) & 3) == 0) refresh();
            deq_store(0);
            if (t + 3 < NSTEPS) load_q();
        }
        compute(8192, 24576);
        __syncthreads();
    }

    const int colb = n0 + wn + lm;
    const int rowb = m0 + wm + (kb_l << 2);
#pragma unroll
    for (int j = 0; j < 4; ++j) {
        const int col = colb + j * 16;
        const float bias_f = bias[col];
#pragma unroll
        for (int i = 0; i < 4; ++i) {
            const int row = rowb + i * 16;
#pragma unroll
            for (int r4 = 0; r4 < 4; ++r4) {
                out[(size_t)(row + r4) * N_DIM + col] = acc[i][j][r4] + bias_f;
            }
        }
    }
}

extern "C" void kernel_launch(void* const* d_in, const int* in_sizes, int n_in,
                              void* d_out, int out_size, void* d_ws, size_t ws_size,
                              hipStream_t stream) {
    const float* x    = (const float*)d_in[0];
    const int* qw     = (const int*)d_in[1];
    const int* qz     = (const int*)d_in[2];
    const float* sc   = (const float*)d_in[3];
    const float* bi   = (const float*)d_in[4];
    float* out        = (float*)d_out;

    const int M = in_sizes[0] / K_DIM;                       // 8192
    const size_t xb_bytes = (size_t)M * K_DIM * 2;           // 64 MiB
    const size_t wb_bytes = (size_t)K_DIM * N_DIM * 2;       // 86 MiB

    if (ws_size >= xb_bytes + wb_bytes) {
        unsigned short* xb2 = (unsigned short*)d_ws;
        unsigned short* wb  = (unsigned short*)((char*)d_ws + xb_bytes);
        cvt_x2<<<dim3(MT2, NKT), 512, 0, stream>>>(x, xb2);
        deq_w4<<<dim3(NTB, NS), 256, 0, stream>>>(qw, qz, sc, wb);
        awq_gemm17<<<dim3(NTB, MT2), 512, 0, stream>>>(xb2, wb, bi, out);
    } else if (ws_size >= xb_bytes) {
        unsigned short* xb = (unsigned short*)d_ws;
        const int n8 = (int)((size_t)M * K_DIM / 8);
        cvt_x<<<2048, 256, 0, stream>>>(x, xb, n8);
        awq_gemm5<true><<<dim3(NT_DIM, M / BM), 256, 0, stream>>>(x, xb, qw, qz, sc, bi, out);
    } else {
        awq_gemm5<false><<<dim3(NT_DIM, M / BM), 256, 0, stream>>>(x, nullptr, qw, qz, sc, bi, out);
    }
}